// Round 12
// baseline (340.298 us; speedup 1.0000x reference)
//
#include <hip/hip_runtime.h>

#define SCALE 128
#define GRID_L 131                        // grid side
#define SLAB (GRID_L * GRID_L)            // 17161 floats per x-slab
#define GRID_V (GRID_L * GRID_L * GRID_L)
#define BATCH 16
#define NPTS 32768                        // points per sample (2^15)
#define NCB 32                            // 2 clouds x 16 samples
#define NBINS 132                         // abs x-bin storage stride (used: 0..128)
#define NB2 264                           // sub-buckets: x-bin * 2 y-halves
#define CAP2 240                          // sub-bucket capacity: mean ~130 + 9.7 sigma

// half-slab tile: 66 rows x 131 cols, +3 shift pad, rounded to float4 multiple
#define HROWS 66
#define HTILE_PAD 8652

typedef float fx4 __attribute__((ext_vector_type(4)));   // nontemporal-store-compatible

// min encoding: enc_d = max over points of (64 - l_d) in [1,128], init 0.
// decode: minoff_d (= min l_d + 64) = 128 - enc_d.
// Sub-bucket split: lo = absy<=64, hi = absy>=64; absy==64 duplicated (dup
// copy flagged at pack bit 15). Gather fast path (minoffy==0): half h reads
// sub-bucket 2*bin+h only (fits exactly: half0 rows [0,66) <-> absy<=64).
// Slow path: read both, skip flagged dups. Row-bounds checks stay as net.

// ---------------------------------------------------------------------------
// FUSED PATH kernel 1: single point pass, block-aggregated slot reservation
// into y-split sub-buckets. 512 blocks x 512 thr, 4 pts/thread (3x float4).
// ---------------------------------------------------------------------------
__global__ void __launch_bounds__(512)
point_pass_kernel(const float* __restrict__ pc,
                  const float* __restrict__ gc,
                  int* __restrict__ minenc,
                  int* __restrict__ cnt,
                  float4* __restrict__ buckets) {
    __shared__ int lh[NB2];               // per-block sub-bucket counts
    __shared__ int gbase[NB2];            // reserved global base per sub-bucket
    __shared__ int red[3 * 8];            // per-wave maxenc, 8 waves

    for (int t = threadIdx.x; t < NB2; t += 512) lh[t] = 0;
    __syncthreads();

    const float s = SCALE * 0.5f;
    int blk = blockIdx.x;                 // 512 blocks, 2048 pts each, 16/cb
    int cb = blk >> 4;                    // 0..15 pred, 16..31 gt
    const float* src = (cb < 16) ? pc : gc;
    int sample = cb & 15;
    int g = ((sample * NPTS + (blk & 15) * 2048) >> 2) + (int)threadIdx.x;
    const fx4* p4 = (const fx4*)src;
    fx4 a = p4[3 * g], b = p4[3 * g + 1], c = p4[3 * g + 2];

    int* cntcb = cnt + cb * NB2;
    float4* dst = buckets + (size_t)cb * NB2 * CAP2;

    float xs[4] = {a.x, a.w, b.z, c.y};
    float ys[4] = {a.y, b.x, b.w, c.z};
    float zs[4] = {a.z, b.y, c.x, c.w};
    int bins2[4], lslot[4], dslot[4];
    float4 pay[4];
    int m0 = 0, m1 = 0, m2 = 0;           // enc = 64 - l, take max
    #pragma unroll
    for (int k = 0; k < 4; ++k) {
        float x = xs[k] * s, y = ys[k] * s, z = zs[k] * s;
        int lx = (int)floorf(x), ly = (int)floorf(y), lz = (int)floorf(z);
        m0 = max(m0, 64 - lx); m1 = max(m1, 64 - ly); m2 = max(m2, 64 - lz);
        dslot[k] = -1;
        if (x + y + z != 0.0f) {
            float fx = x - (float)lx, fy = y - (float)ly, fz = z - (float)lz;
            int absx = lx + 64, absy = ly + 64, absz = lz + 64;
            // primary: lo unless absy>64; absy==64 duplicated into hi
            bins2[k] = absx * 2 + (absy > 64 ? 1 : 0);
            lslot[k] = atomicAdd(&lh[bins2[k]], 1);
            if (absy == 64) dslot[k] = atomicAdd(&lh[absx * 2 + 1], 1);
            pay[k] = make_float4(fx, fy, fz,
                                 __int_as_float(absy | (absz << 16)));
        } else {
            bins2[k] = -1;
        }
    }
    __syncthreads();

    // bulk reservation: one global atomic per non-empty (block, sub-bucket)
    for (int t = threadIdx.x; t < NB2; t += 512) {
        int c2 = lh[t];
        gbase[t] = c2 ? atomicAdd(&cntcb[t], c2) : 0;
    }
    __syncthreads();

    // payload writes (primary + flagged duplicate for absy==64)
    #pragma unroll
    for (int k = 0; k < 4; ++k) {
        if (bins2[k] >= 0) {
            int slot = gbase[bins2[k]] + lslot[k];
            if (slot < CAP2)              // clamp (P(overflow) ~ 1e-15)
                dst[bins2[k] * CAP2 + slot] = pay[k];
            if (dslot[k] >= 0) {
                int db = bins2[k] + 1;    // primary was lo (absy==64 -> lo)
                int ds = gbase[db] + dslot[k];
                if (ds < CAP2) {
                    float4 pd = pay[k];
                    pd.w = __int_as_float(__float_as_int(pd.w) | 0x8000);
                    dst[db * CAP2 + ds] = pd;
                }
            }
        }
    }

    // wave-64 max reduction of enc (8 waves/block)
    #pragma unroll
    for (int off = 32; off > 0; off >>= 1) {
        m0 = max(m0, __shfl_down(m0, off));
        m1 = max(m1, __shfl_down(m1, off));
        m2 = max(m2, __shfl_down(m2, off));
    }
    int wave = threadIdx.x >> 6;
    if ((threadIdx.x & 63) == 0) {
        red[3 * wave + 0] = m0;
        red[3 * wave + 1] = m1;
        red[3 * wave + 2] = m2;
    }
    __syncthreads();
    if (threadIdx.x < 3) {
        int m = red[threadIdx.x];
        #pragma unroll
        for (int w = 1; w < 8; ++w) m = max(m, red[3 * w + threadIdx.x]);
        atomicMax(&minenc[threadIdx.x], m);
    }
}

// ---------------------------------------------------------------------------
// LEGACY PATH (ws too small for buckets): R3's kernels, enc-adapted.
// ---------------------------------------------------------------------------
__global__ void __launch_bounds__(1024)
min_hist_kernel(const float* __restrict__ pc,
                const float* __restrict__ gc,
                int* __restrict__ minenc,
                int* __restrict__ counts) {
    __shared__ int h[NBINS];
    __shared__ int red[3 * 16];

    for (int t = threadIdx.x; t < NBINS; t += 1024) h[t] = 0;
    __syncthreads();

    const float s = SCALE * 0.5f;
    int blk = blockIdx.x;
    const float* src = (blk < 128) ? pc : gc;
    int jbase = (blk & 127) * 4096;
    const fx4* p4 = (const fx4*)(src + (size_t)3 * jbase);
    int t3 = 3 * (int)threadIdx.x;
    fx4 a = p4[t3], b = p4[t3 + 1], c = p4[t3 + 2];

    float xs[4] = {a.x, a.w, b.z, c.y};
    float ys[4] = {a.y, b.x, b.w, c.z};
    float zs[4] = {a.z, b.y, c.x, c.w};
    int m0 = 0, m1 = 0, m2 = 0;
    #pragma unroll
    for (int k = 0; k < 4; ++k) {
        float x = xs[k] * s, y = ys[k] * s, z = zs[k] * s;
        int lx = (int)floorf(x), ly = (int)floorf(y), lz = (int)floorf(z);
        if (x + y + z != 0.0f) atomicAdd(&h[lx + 64], 1);
        m0 = max(m0, 64 - lx); m1 = max(m1, 64 - ly); m2 = max(m2, 64 - lz);
    }
    #pragma unroll
    for (int off = 32; off > 0; off >>= 1) {
        m0 = max(m0, __shfl_down(m0, off));
        m1 = max(m1, __shfl_down(m1, off));
        m2 = max(m2, __shfl_down(m2, off));
    }
    int wave = threadIdx.x >> 6;
    if ((threadIdx.x & 63) == 0) {
        red[3 * wave + 0] = m0;
        red[3 * wave + 1] = m1;
        red[3 * wave + 2] = m2;
    }
    __syncthreads();
    if (threadIdx.x < 3) {
        int m = red[threadIdx.x];
        #pragma unroll
        for (int w = 1; w < 16; ++w) m = max(m, red[3 * w + threadIdx.x]);
        atomicMax(&minenc[threadIdx.x], m);
    }
    int cb = (blk >> 7) * 16 + ((blk & 127) >> 3);
    for (int t = threadIdx.x; t < NBINS; t += 1024) {
        int c2 = h[t];
        if (c2) atomicAdd(&counts[cb * NBINS + t], c2);
    }
}

__global__ void scan_kernel(const int* __restrict__ counts,
                            int* __restrict__ starts,
                            int* __restrict__ cursor) {
    int cb = threadIdx.x;
    if (cb >= NCB) return;
    int acc = 0;
    #pragma unroll 4
    for (int bin = 0; bin < NBINS; ++bin) {
        starts[cb * (NBINS + 1) + bin] = acc;
        cursor[cb * NBINS + bin] = acc;
        acc += counts[cb * NBINS + bin];
    }
    starts[cb * (NBINS + 1) + NBINS] = acc;
}

__global__ void __launch_bounds__(256)
reorder_kernel(const float* __restrict__ pc,
               const float* __restrict__ gc,
               int* __restrict__ cursor,
               float4* __restrict__ sorted) {
    int gtid = blockIdx.x * 256 + threadIdx.x;
    const float s = SCALE * 0.5f;
    const float* src = (gtid < 131072) ? pc : gc;
    int q = gtid & 131071;
    const fx4* p4 = (const fx4*)src;
    fx4 a = p4[3 * q], b = p4[3 * q + 1], c = p4[3 * q + 2];

    int cb = (gtid * 4) >> 15;
    float4* dst = sorted + (size_t)cb * NPTS;
    int* cur = cursor + cb * NBINS;

    float xs[4] = {a.x, a.w, b.z, c.y};
    float ys[4] = {a.y, b.x, b.w, c.z};
    float zs[4] = {a.z, b.y, c.x, c.w};
    #pragma unroll
    for (int k = 0; k < 4; ++k) {
        float x = xs[k] * s, y = ys[k] * s, z = zs[k] * s;
        if (x + y + z == 0.0f) continue;
        int lx = (int)floorf(x), ly = (int)floorf(y), lz = (int)floorf(z);
        float fx = x - (float)lx, fy = y - (float)ly, fz = z - (float)lz;
        int slot = atomicAdd(&cur[lx + 64], 1);
        dst[slot] =
            make_float4(fx, fy, fz, __int_as_float((ly + 64) | ((lz + 64) << 16)));
    }
}

// ---------------------------------------------------------------------------
// Gather: one 512-thread block per (cb, ix, y-half). BUCKET=true reads y-split
// sub-buckets (fast path minoffy==0: own sub-bucket only; slow path: both,
// skipping flagged dups). BUCKET=false reads dense sorted[] via starts[].
// 34.6 KB LDS -> 4 blocks/CU.
// ---------------------------------------------------------------------------
template<bool BUCKET>
__global__ void __launch_bounds__(512)
gather_kernel(const float4* __restrict__ pts_base,
              const int* __restrict__ meta,
              const int* __restrict__ minenc,
              float* __restrict__ out) {
    __shared__ __align__(16) float tile[HTILE_PAD];

    // bijective XCD-chunk swizzle: 8384 blocks = 8 * 1048 exactly.
    int orig = blockIdx.x;
    int blk = (orig & 7) * 1048 + (orig >> 3);

    int h  = blk & 1;
    int t2 = blk >> 1;                    // cb*GRID_L + ix
    int cb = t2 / GRID_L;
    int ix = t2 - cb * GRID_L;

    int base = HROWS * h;                 // first slab row owned by this block
    int rows = h ? (GRID_L - HROWS) : HROWS;   // 65 : 66
    int N = rows * GRID_L;                // floats to emit
    int base_dw = cb * GRID_V + ix * SLAB + base * GRID_L;
    int SHIFT = base_dw & 3;
    int i0 = (4 - SHIFT) & 3;

    int minoffx = 128 - minenc[0];        // = min lx + 64
    int minoffy = 128 - minenc[1];
    int minoffz = 128 - minenc[2];

    fx4* tz = (fx4*)tile;
    for (int t = threadIdx.x; t < HTILE_PAD / 4; t += 512)
        tz[t] = (fx4){0.0f, 0.0f, 0.0f, 0.0f};
    __syncthreads();

    const float4* pts = BUCKET ? pts_base : pts_base + (size_t)cb * NPTS;
    bool fastY = (minoffy == 0);

    #pragma unroll
    for (int pass = 0; pass < 2; ++pass) {
        int bin = ix - 2 + pass + minoffx;
        if (bin < 0 || bin >= NBINS) continue;
        int nsb = (!BUCKET || fastY) ? 1 : 2;
        for (int si = 0; si < nsb; ++si) {
            int b0, b1;
            bool scanBoth = false;
            if (BUCKET) {
                int sb = fastY ? (2 * bin + h) : (2 * bin + si);
                scanBoth = !fastY;
                b0 = (cb * NB2 + sb) * CAP2;
                int c = meta[cb * NB2 + sb];
                b1 = b0 + min(c, CAP2);
            } else {
                const int* st = meta + cb * (NBINS + 1);
                b0 = st[bin]; b1 = st[bin + 1];
            }
            for (int p = b0 + (int)threadIdx.x; p < b1; p += 512) {
                float4 q = pts[p];
                int pack = __float_as_int(q.w);
                if (scanBoth && (pack & 0x8000)) continue;   // skip dup copy
                int py = (pack & 0x7fff) - minoffy + 1;   // lower y vertex
                int pz = (pack >> 16) - minoffz + 1;      // lower z vertex
                float wx  = pass ? (1.0f - q.x) : q.x;
                float wz0 = wx * (1.0f - q.z);
                float wz1 = wx * q.z;
                int r0 = py - base;
                if (r0 >= 0 && r0 < rows) {
                    float wy0 = 1.0f - q.y;
                    float* t0 = &tile[r0 * GRID_L + pz + SHIFT];
                    atomicAdd(t0,     wy0 * wz0);
                    atomicAdd(t0 + 1, wy0 * wz1);
                }
                int r1 = r0 + 1;
                if (r1 >= 0 && r1 < rows) {
                    float wy1 = q.y;
                    float* t1 = &tile[r1 * GRID_L + pz + SHIFT];
                    atomicAdd(t1,     wy1 * wz0);
                    atomicAdd(t1 + 1, wy1 * wz1);
                }
            }
        }
    }
    __syncthreads();

    float* o = out + base_dw;
    if ((int)threadIdx.x < i0)
        __builtin_nontemporal_store(tile[threadIdx.x + SHIFT], &o[threadIdx.x]);
    int n4 = (N - i0) >> 2;
    const fx4* t4 = (const fx4*)&tile[i0 + SHIFT];
    fx4* o4 = (fx4*)&o[i0];
    for (int k = threadIdx.x; k < n4; k += 512)
        __builtin_nontemporal_store(t4[k], &o4[k]);
    int tail0 = i0 + 4 * n4;
    int tt = tail0 + (int)threadIdx.x;
    if (tt < N)
        __builtin_nontemporal_store(tile[tt + SHIFT], &o[tt]);
}

extern "C" void kernel_launch(void* const* d_in, const int* in_sizes, int n_in,
                              void* d_out, int out_size, void* d_ws, size_t ws_size,
                              hipStream_t stream) {
    const float* pred = (const float*)d_in[0];
    const float* gt   = (const float*)d_in[1];
    float* out = (float*)d_out;   // [2, BATCH, GRID_V]: pred grids then gt grids

    char* w = (char*)d_ws;
    int* minenc = (int*)w;                             // 3 ints (16B slot), init 0

    // fused-path need: 16 + cnt(NCB*NB2*4, pad to 16) + buckets (~32.4 MB)
    size_t cnt_bytes = ((sizeof(int) * (size_t)(NCB * NB2)) + 15) & ~(size_t)15;
    size_t bucket_bytes = sizeof(float4) * (size_t)NCB * NB2 * CAP2;
    size_t need = 16 + cnt_bytes + bucket_bytes;

    if (ws_size >= need) {
        // -------- fused path: 1 memset + 2 kernels --------
        int* cnt = (int*)(w + 16);
        float4* buckets = (float4*)(w + 16 + cnt_bytes);

        // single zero-memset covers minenc (enc init 0) AND cnt
        hipMemsetAsync(w, 0, 16 + sizeof(int) * NCB * NB2, stream);

        point_pass_kernel<<<512, 512, 0, stream>>>(pred, gt, minenc, cnt, buckets);
        gather_kernel<true><<<NCB * GRID_L * 2, 512, 0, stream>>>(
            buckets, cnt, minenc, out);
    } else {
        // -------- legacy path: 1 memset + 4 kernels --------
        int* counts = (int*)(w + 16);                  // NCB*NBINS
        int* starts = counts + NCB * NBINS;            // NCB*(NBINS+1)
        int* cursor = starts + NCB * (NBINS + 1);      // NCB*NBINS
        size_t off = 16 + sizeof(int) *
            (size_t)(NCB * NBINS + NCB * (NBINS + 1) + NCB * NBINS);
        off = (off + 15) & ~(size_t)15;
        float4* sorted = (float4*)(w + off);           // NCB*NPTS float4 = 16 MB

        hipMemsetAsync(w, 0, 16 + sizeof(int) * NCB * NBINS, stream);

        min_hist_kernel<<<256, 1024, 0, stream>>>(pred, gt, minenc, counts);
        scan_kernel<<<1, 64, 0, stream>>>(counts, starts, cursor);
        reorder_kernel<<<1024, 256, 0, stream>>>(pred, gt, cursor, sorted);
        gather_kernel<false><<<NCB * GRID_L * 2, 512, 0, stream>>>(
            sorted, starts, minenc, out);
    }
}

// Round 13
// 327.584 us; speedup vs baseline: 1.0388x; 1.0388x over previous
//
#include <hip/hip_runtime.h>

#define SCALE 128
#define GRID_L 131                        // grid side
#define SLAB (GRID_L * GRID_L)            // 17161 floats per x-slab
#define GRID_V (GRID_L * GRID_L * GRID_L)
#define BATCH 16
#define NPTS 32768                        // points per sample (2^15)
#define NCB 32                            // 2 clouds x 16 samples
#define NBINS 132                         // abs x-bin storage stride (used: 0..128)
#define CAP 384                           // bucket capacity: mean 256 + 8 sigma

// half-slab tile: 66 rows x 131 cols, +3 shift pad, rounded to float4 multiple
#define HROWS 66
#define HTILE_PAD 8652

typedef float fx4 __attribute__((ext_vector_type(4)));   // nontemporal-store-compatible

// min encoding: enc_d = max over points of (64 - l_d) in [1,128], init 0.
// decode: minoff_d (= min l_d + 64) = 128 - enc_d.
// Lets mins share one contiguous ZERO memset with the cnt array.

// ---------------------------------------------------------------------------
// FUSED PATH kernel 1 (best-measured R8/R10 structure): single point pass,
// block-aggregated slot reservation:
//   phase 1: LDS hist atomicAdd -> per-point local slot
//   phase 2: ONE global atomicAdd per (block,bin) reserves a contiguous range
//   phase 3: payload stored at bucket[bin]*CAP + gbase[bin] + lslot
// Also computes per-axis min (ALL points, incl. padding, per reference).
// 512 blocks x 512 thr, 2048 points/block (4 pts/thread, 3x float4 loads).
// ---------------------------------------------------------------------------
__global__ void __launch_bounds__(512)
point_pass_kernel(const float* __restrict__ pc,
                  const float* __restrict__ gc,
                  int* __restrict__ minenc,
                  int* __restrict__ cnt,
                  float4* __restrict__ buckets) {
    __shared__ int lh[NBINS];             // per-block bin counts
    __shared__ int gbase[NBINS];          // reserved global base per bin
    __shared__ int red[3 * 8];            // per-wave maxenc, 8 waves

    for (int t = threadIdx.x; t < NBINS; t += 512) lh[t] = 0;
    __syncthreads();

    const float s = SCALE * 0.5f;
    int blk = blockIdx.x;                 // 512 blocks, 2048 pts each, 16/cb
    int cb = blk >> 4;                    // 0..15 pred, 16..31 gt
    const float* src = (cb < 16) ? pc : gc;
    int sample = cb & 15;
    int g = ((sample * NPTS + (blk & 15) * 2048) >> 2) + (int)threadIdx.x;
    const fx4* p4 = (const fx4*)src;
    fx4 a = p4[3 * g], b = p4[3 * g + 1], c = p4[3 * g + 2];

    int* cntcb = cnt + cb * NBINS;
    float4* dst = buckets + (size_t)cb * NBINS * CAP;

    float xs[4] = {a.x, a.w, b.z, c.y};
    float ys[4] = {a.y, b.x, b.w, c.z};
    float zs[4] = {a.z, b.y, c.x, c.w};
    int bins[4], lslot[4];
    float4 pay[4];
    int m0 = 0, m1 = 0, m2 = 0;           // enc = 64 - l, take max
    #pragma unroll
    for (int k = 0; k < 4; ++k) {
        float x = xs[k] * s, y = ys[k] * s, z = zs[k] * s;
        int lx = (int)floorf(x), ly = (int)floorf(y), lz = (int)floorf(z);
        m0 = max(m0, 64 - lx); m1 = max(m1, 64 - ly); m2 = max(m2, 64 - lz);
        if (x + y + z != 0.0f) {
            float fx = x - (float)lx, fy = y - (float)ly, fz = z - (float)lz;
            bins[k] = lx + 64;
            lslot[k] = atomicAdd(&lh[bins[k]], 1);
            pay[k] = make_float4(
                fx, fy, fz, __int_as_float((ly + 64) | ((lz + 64) << 16)));
        } else {
            bins[k] = -1;
        }
    }
    __syncthreads();

    // phase 2: bulk reservation, one global atomic per non-empty (block,bin)
    for (int t = threadIdx.x; t < NBINS; t += 512) {
        int c2 = lh[t];
        gbase[t] = c2 ? atomicAdd(&cntcb[t], c2) : 0;
    }
    __syncthreads();

    // phase 3: payload writes
    #pragma unroll
    for (int k = 0; k < 4; ++k) {
        if (bins[k] >= 0) {
            int slot = gbase[bins[k]] + lslot[k];
            if (slot < CAP)               // clamp (P(overflow) ~ 1e-12)
                dst[bins[k] * CAP + slot] = pay[k];
        }
    }

    // wave-64 max reduction of enc (8 waves/block)
    #pragma unroll
    for (int off = 32; off > 0; off >>= 1) {
        m0 = max(m0, __shfl_down(m0, off));
        m1 = max(m1, __shfl_down(m1, off));
        m2 = max(m2, __shfl_down(m2, off));
    }
    int wave = threadIdx.x >> 6;
    if ((threadIdx.x & 63) == 0) {
        red[3 * wave + 0] = m0;
        red[3 * wave + 1] = m1;
        red[3 * wave + 2] = m2;
    }
    __syncthreads();
    if (threadIdx.x < 3) {
        int m = red[threadIdx.x];
        #pragma unroll
        for (int w = 1; w < 8; ++w) m = max(m, red[3 * w + threadIdx.x]);
        atomicMax(&minenc[threadIdx.x], m);
    }
}

// ---------------------------------------------------------------------------
// LEGACY PATH (ws too small for buckets): R3's kernels, enc-adapted.
// ---------------------------------------------------------------------------
__global__ void __launch_bounds__(1024)
min_hist_kernel(const float* __restrict__ pc,
                const float* __restrict__ gc,
                int* __restrict__ minenc,
                int* __restrict__ counts) {
    __shared__ int h[NBINS];
    __shared__ int red[3 * 16];

    for (int t = threadIdx.x; t < NBINS; t += 1024) h[t] = 0;
    __syncthreads();

    const float s = SCALE * 0.5f;
    int blk = blockIdx.x;
    const float* src = (blk < 128) ? pc : gc;
    int jbase = (blk & 127) * 4096;
    const fx4* p4 = (const fx4*)(src + (size_t)3 * jbase);
    int t3 = 3 * (int)threadIdx.x;
    fx4 a = p4[t3], b = p4[t3 + 1], c = p4[t3 + 2];

    float xs[4] = {a.x, a.w, b.z, c.y};
    float ys[4] = {a.y, b.x, b.w, c.z};
    float zs[4] = {a.z, b.y, c.x, c.w};
    int m0 = 0, m1 = 0, m2 = 0;
    #pragma unroll
    for (int k = 0; k < 4; ++k) {
        float x = xs[k] * s, y = ys[k] * s, z = zs[k] * s;
        int lx = (int)floorf(x), ly = (int)floorf(y), lz = (int)floorf(z);
        if (x + y + z != 0.0f) atomicAdd(&h[lx + 64], 1);
        m0 = max(m0, 64 - lx); m1 = max(m1, 64 - ly); m2 = max(m2, 64 - lz);
    }
    #pragma unroll
    for (int off = 32; off > 0; off >>= 1) {
        m0 = max(m0, __shfl_down(m0, off));
        m1 = max(m1, __shfl_down(m1, off));
        m2 = max(m2, __shfl_down(m2, off));
    }
    int wave = threadIdx.x >> 6;
    if ((threadIdx.x & 63) == 0) {
        red[3 * wave + 0] = m0;
        red[3 * wave + 1] = m1;
        red[3 * wave + 2] = m2;
    }
    __syncthreads();
    if (threadIdx.x < 3) {
        int m = red[threadIdx.x];
        #pragma unroll
        for (int w = 1; w < 16; ++w) m = max(m, red[3 * w + threadIdx.x]);
        atomicMax(&minenc[threadIdx.x], m);
    }
    int cb = (blk >> 7) * 16 + ((blk & 127) >> 3);
    for (int t = threadIdx.x; t < NBINS; t += 1024) {
        int c2 = h[t];
        if (c2) atomicAdd(&counts[cb * NBINS + t], c2);
    }
}

__global__ void scan_kernel(const int* __restrict__ counts,
                            int* __restrict__ starts,
                            int* __restrict__ cursor) {
    int cb = threadIdx.x;
    if (cb >= NCB) return;
    int acc = 0;
    #pragma unroll 4
    for (int bin = 0; bin < NBINS; ++bin) {
        starts[cb * (NBINS + 1) + bin] = acc;
        cursor[cb * NBINS + bin] = acc;
        acc += counts[cb * NBINS + bin];
    }
    starts[cb * (NBINS + 1) + NBINS] = acc;
}

__global__ void __launch_bounds__(256)
reorder_kernel(const float* __restrict__ pc,
               const float* __restrict__ gc,
               int* __restrict__ cursor,
               float4* __restrict__ sorted) {
    int gtid = blockIdx.x * 256 + threadIdx.x;
    const float s = SCALE * 0.5f;
    const float* src = (gtid < 131072) ? pc : gc;
    int q = gtid & 131071;
    const fx4* p4 = (const fx4*)src;
    fx4 a = p4[3 * q], b = p4[3 * q + 1], c = p4[3 * q + 2];

    int cb = (gtid * 4) >> 15;
    float4* dst = sorted + (size_t)cb * NPTS;
    int* cur = cursor + cb * NBINS;

    float xs[4] = {a.x, a.w, b.z, c.y};
    float ys[4] = {a.y, b.x, b.w, c.z};
    float zs[4] = {a.z, b.y, c.x, c.w};
    #pragma unroll
    for (int k = 0; k < 4; ++k) {
        float x = xs[k] * s, y = ys[k] * s, z = zs[k] * s;
        if (x + y + z == 0.0f) continue;
        int lx = (int)floorf(x), ly = (int)floorf(y), lz = (int)floorf(z);
        float fx = x - (float)lx, fy = y - (float)ly, fz = z - (float)lz;
        int slot = atomicAdd(&cur[lx + 64], 1);
        dst[slot] =
            make_float4(fx, fy, fz, __int_as_float((ly + 64) | ((lz + 64) << 16)));
    }
}

// ---------------------------------------------------------------------------
// Gather: one 512-thread block per (cb, ix, y-half). BUCKET=true reads
// fixed-capacity buckets via cnt[]; BUCKET=false reads dense sorted[] via
// starts[]. minenc decode: minoff = 128 - enc. 34.6 KB LDS -> 4 blocks/CU.
// ---------------------------------------------------------------------------
template<bool BUCKET>
__global__ void __launch_bounds__(512)
gather_kernel(const float4* __restrict__ pts_base,
              const int* __restrict__ meta,
              const int* __restrict__ minenc,
              float* __restrict__ out) {
    __shared__ __align__(16) float tile[HTILE_PAD];

    // bijective XCD-chunk swizzle: 8384 blocks = 8 * 1048 exactly.
    int orig = blockIdx.x;
    int blk = (orig & 7) * 1048 + (orig >> 3);

    int h  = blk & 1;
    int t2 = blk >> 1;                    // cb*GRID_L + ix
    int cb = t2 / GRID_L;
    int ix = t2 - cb * GRID_L;

    int base = HROWS * h;                 // first slab row owned by this block
    int rows = h ? (GRID_L - HROWS) : HROWS;   // 65 : 66
    int N = rows * GRID_L;                // floats to emit
    int base_dw = cb * GRID_V + ix * SLAB + base * GRID_L;
    int SHIFT = base_dw & 3;
    int i0 = (4 - SHIFT) & 3;

    int minoffx = 128 - minenc[0];        // = min lx + 64
    int minoffy = 128 - minenc[1];
    int minoffz = 128 - minenc[2];

    fx4* tz = (fx4*)tile;
    for (int t = threadIdx.x; t < HTILE_PAD / 4; t += 512)
        tz[t] = (fx4){0.0f, 0.0f, 0.0f, 0.0f};
    __syncthreads();

    const float4* pts = BUCKET ? pts_base : pts_base + (size_t)cb * NPTS;

    #pragma unroll
    for (int pass = 0; pass < 2; ++pass) {
        int bin = ix - 2 + pass + minoffx;
        if (bin < 0 || bin >= NBINS) continue;
        int b0, b1;
        if (BUCKET) {
            b0 = (cb * NBINS + bin) * CAP;
            int c = meta[cb * NBINS + bin];
            b1 = b0 + min(c, CAP);
        } else {
            const int* st = meta + cb * (NBINS + 1);
            b0 = st[bin]; b1 = st[bin + 1];
        }
        for (int p = b0 + (int)threadIdx.x; p < b1; p += 512) {
            float4 q = pts[p];
            int pack = __float_as_int(q.w);
            int py = (pack & 0xffff) - minoffy + 1;   // lower y vertex
            int pz = (pack >> 16) - minoffz + 1;      // lower z vertex
            float wx  = pass ? (1.0f - q.x) : q.x;
            float wz0 = wx * (1.0f - q.z);
            float wz1 = wx * q.z;
            int r0 = py - base;
            if (r0 >= 0 && r0 < rows) {
                float wy0 = 1.0f - q.y;
                float* t0 = &tile[r0 * GRID_L + pz + SHIFT];
                atomicAdd(t0,     wy0 * wz0);
                atomicAdd(t0 + 1, wy0 * wz1);
            }
            int r1 = r0 + 1;
            if (r1 >= 0 && r1 < rows) {
                float wy1 = q.y;
                float* t1 = &tile[r1 * GRID_L + pz + SHIFT];
                atomicAdd(t1,     wy1 * wz0);
                atomicAdd(t1 + 1, wy1 * wz1);
            }
        }
    }
    __syncthreads();

    float* o = out + base_dw;
    if ((int)threadIdx.x < i0)
        __builtin_nontemporal_store(tile[threadIdx.x + SHIFT], &o[threadIdx.x]);
    int n4 = (N - i0) >> 2;
    const fx4* t4 = (const fx4*)&tile[i0 + SHIFT];
    fx4* o4 = (fx4*)&o[i0];
    for (int k = threadIdx.x; k < n4; k += 512)
        __builtin_nontemporal_store(t4[k], &o4[k]);
    int tail0 = i0 + 4 * n4;
    int tt = tail0 + (int)threadIdx.x;
    if (tt < N)
        __builtin_nontemporal_store(tile[tt + SHIFT], &o[tt]);
}

extern "C" void kernel_launch(void* const* d_in, const int* in_sizes, int n_in,
                              void* d_out, int out_size, void* d_ws, size_t ws_size,
                              hipStream_t stream) {
    const float* pred = (const float*)d_in[0];
    const float* gt   = (const float*)d_in[1];
    float* out = (float*)d_out;   // [2, BATCH, GRID_V]: pred grids then gt grids

    char* w = (char*)d_ws;
    int* minenc = (int*)w;                             // 3 ints (16B slot), init 0

    // fused-path need: 16 + cnt(NCB*NBINS*4, pad to 16) + buckets
    size_t cnt_bytes = ((sizeof(int) * (size_t)(NCB * NBINS)) + 15) & ~(size_t)15;
    size_t bucket_bytes = sizeof(float4) * (size_t)NCB * NBINS * CAP;   // ~25.9 MB
    size_t need = 16 + cnt_bytes + bucket_bytes;

    if (ws_size >= need) {
        // -------- fused path: 1 memset + 2 kernels --------
        int* cnt = (int*)(w + 16);
        float4* buckets = (float4*)(w + 16 + cnt_bytes);

        // single zero-memset covers minenc (enc init 0) AND cnt
        hipMemsetAsync(w, 0, 16 + sizeof(int) * NCB * NBINS, stream);

        point_pass_kernel<<<512, 512, 0, stream>>>(pred, gt, minenc, cnt, buckets);
        gather_kernel<true><<<NCB * GRID_L * 2, 512, 0, stream>>>(
            buckets, cnt, minenc, out);
    } else {
        // -------- legacy path: 1 memset + 4 kernels --------
        int* counts = (int*)(w + 16);                  // NCB*NBINS
        int* starts = counts + NCB * NBINS;            // NCB*(NBINS+1)
        int* cursor = starts + NCB * (NBINS + 1);      // NCB*NBINS
        size_t off = 16 + sizeof(int) *
            (size_t)(NCB * NBINS + NCB * (NBINS + 1) + NCB * NBINS);
        off = (off + 15) & ~(size_t)15;
        float4* sorted = (float4*)(w + off);           // NCB*NPTS float4 = 16 MB

        hipMemsetAsync(w, 0, 16 + sizeof(int) * NCB * NBINS, stream);

        min_hist_kernel<<<256, 1024, 0, stream>>>(pred, gt, minenc, counts);
        scan_kernel<<<1, 64, 0, stream>>>(counts, starts, cursor);
        reorder_kernel<<<1024, 256, 0, stream>>>(pred, gt, cursor, sorted);
        gather_kernel<false><<<NCB * GRID_L * 2, 512, 0, stream>>>(
            sorted, starts, minenc, out);
    }
}